// Round 13
// baseline (75.962 us; speedup 1.0000x reference)
//
#include <hip/hip_runtime.h>
#include <hip/hip_fp16.h>

#define BATCH 32
#define TLEN  4096
#define CH    128      // C == F == 128
#define KW    3
#define DIL   8

#define BM    128                // output rows per block
#define HR    (BM + 2 * DIL)     // 144  h rows needed
#define WROWS (BM + 4 * DIL)     // 160  x rows needed
#define LDSC  132                // 264B stride = 66 dwords ≡ 2 (mod 32): ~2-way
                                 // bank alias (free). 136 (≡4 mod 32) gave 8-way
                                 // conflicts (r6-r11). Keep stride ≢ 0/4 mod 32.

typedef _Float16 f16x8 __attribute__((ext_vector_type(8)));
typedef _Float16 f16x4 __attribute__((ext_vector_type(4)));
typedef float    f32x4 __attribute__((ext_vector_type(4)));

// ---------------------------------------------------------------------------
// Prep: Wt[j][f][c] = (f16) W[c][j][f]   for both layers' kernels.
// W is (C, K, F) row-major: W[c*KW*CH + j*CH + f].
// ---------------------------------------------------------------------------
__global__ void prep_weights_kernel(const float* __restrict__ W1,
                                    const float* __restrict__ W2,
                                    _Float16* __restrict__ Wt1,
                                    _Float16* __restrict__ Wt2) {
    const int total = KW * CH * CH;
    int idx = blockIdx.x * 256 + threadIdx.x;
    if (idx >= 2 * total) return;
    const float* W  = (idx < total) ? W1 : W2;
    _Float16*    Wt = (idx < total) ? Wt1 : Wt2;
    int r = idx % total;
    int j = r / (CH * CH);
    int f = (r / CH) % CH;
    int c = r % CH;
    Wt[j * CH * CH + f * CH + c] = (_Float16)W[c * (KW * CH) + j * CH + f];
}

// ---------------------------------------------------------------------------
// Fused TemporalDeConvBlock — SWAPPED-OPERAND build.
// D = mfma(W-frag, X-frag) gives D[row=f][col=t]: lane holds 4 CONSECUTIVE
// f values at fixed t (f = nc+nn*16+kg*4+i, t = t0+m*16+l15). Operand loads
// are bit-identical to the unswapped version (verified m89 layouts: A wants
// W[f][c] c-contig = our w load; B wants x[t][c] c-contig = our af read).
// Payoff: h-store 72 ds_write_b16 -> 18 ds_write_b64; epilogue 64+64 scalar
// dword ops -> 16+16 dwordx4; nv uniform per m; bias as f32x4.
// 256 thr = 4 waves; wave w owns cols [32w,32w+32) as two 16-col subtiles.
// BM=128, single aliased LDS buffer (x window then h window), residual from
// global x, XCD-aware bijective block swizzle (grid 1024 = 8*128).
// LESSONS: caps below live-set spill (r3/r5); 512-thr blocks pinned to 64
// VGPR (r4/r6/r7); occupancy not the limiter (r8 vs r11); LDSC mod-32 rule.
// ---------------------------------------------------------------------------
__global__ __launch_bounds__(256)
void fused_deconv_kernel(const float* __restrict__ x,
                         const _Float16* __restrict__ Wt1,
                         const float* __restrict__ bias1,
                         const _Float16* __restrict__ Wt2,
                         const float* __restrict__ bias2,
                         float* __restrict__ out)
{
    __shared__ __align__(16) _Float16 buf[WROWS][LDSC];   // 160*264 = 42240 B

    const int tid  = threadIdx.x;
    const int lane = tid & 63;
    const int wid  = tid >> 6;         // 0..3
    const int l15  = lane & 15;
    const int kg   = lane >> 4;        // 0..3
    const int nc   = wid << 5;         // wave column base: 0,32,64,96

    // XCD-aware bijective swizzle: grid = 1024 = 8 XCDs x 128 chunks.
    const int bt0 = blockIdx.x;
    const int bt  = (bt0 & 7) * 128 + (bt0 >> 3);

    const int b  = bt >> 5;            // TLEN/BM = 32 tiles per batch
    const int t0 = (bt & 31) << 7;

    // ---- prefetch GEMM1 weight fragments (24 x 16B = 96 VGPRs); L2 latency
    // overlaps the x staging below. (A-operand of the swapped MFMA.)
    f16x8 w1[12][2];
#pragma unroll
    for (int ks = 0; ks < 12; ++ks) {
        const int j  = ks >> 2;
        const int c0 = (ks & 3) << 5;
        const _Float16* wb = Wt1 + (size_t)j * (CH * CH) + c0 + kg * 8;
        w1[ks][0] = *(const f16x8*)(wb + (nc + l15) * CH);
        w1[ks][1] = *(const f16x8*)(wb + (nc + 16 + l15) * CH);
    }

    // ---- stage x window (f32 -> f16), rows t0..t0+159, zero past TLEN.
#pragma unroll
    for (int p = 0; p < 10; ++p) {
        const int i   = tid + 256 * p;
        const int row = i >> 4;
        const int c8  = (i & 15) << 3;
        const int t   = t0 + row;
        f16x8 o;
        if (t < TLEN) {
            const float* xp = x + ((size_t)b * TLEN + t) * CH + c8;
            f32x4 v0 = *(const f32x4*)(xp + 0);
            f32x4 v1 = *(const f32x4*)(xp + 4);
            o[0] = (_Float16)v0[0]; o[1] = (_Float16)v0[1];
            o[2] = (_Float16)v0[2]; o[3] = (_Float16)v0[3];
            o[4] = (_Float16)v1[0]; o[5] = (_Float16)v1[1];
            o[6] = (_Float16)v1[2]; o[7] = (_Float16)v1[3];
        } else {
            o = (f16x8){};
        }
        *(f16x8*)&buf[row][c8] = o;
    }

    // bias vectors: f = nc + nn*16 + kg*4 + i  (i = acc reg index)
    const f32x4 bv1_0 = *(const f32x4*)&bias1[nc + kg * 4];
    const f32x4 bv1_1 = *(const f32x4*)&bias1[nc + 16 + kg * 4];
    const f32x4 bv2_0 = *(const f32x4*)&bias2[nc + kg * 4];
    const f32x4 bv2_1 = *(const f32x4*)&bias2[nc + 16 + kg * 4];

    __syncthreads();

    // ---- GEMM1: h rows 0..143, cols [nc,nc+32) — 216 MFMA / 108 ds_read
    f32x4 acc1[9][2];
#pragma unroll
    for (int m = 0; m < 9; ++m) {
        acc1[m][0] = (f32x4){0.f, 0.f, 0.f, 0.f};
        acc1[m][1] = (f32x4){0.f, 0.f, 0.f, 0.f};
    }
#pragma unroll
    for (int ks = 0; ks < 12; ++ks) {
        const int j     = ks >> 2;
        const int c0    = (ks & 3) << 5;
        const int shift = (2 - j) * DIL;
#pragma unroll
        for (int m = 0; m < 9; ++m) {
            f16x8 af = *(const f16x8*)&buf[m * 16 + shift + l15][c0 + kg * 8];
            // SWAPPED: D[f][t] = W x X  (operand loads unchanged)
            acc1[m][0] = __builtin_amdgcn_mfma_f32_16x16x32_f16(w1[ks][0], af, acc1[m][0], 0, 0, 0);
            acc1[m][1] = __builtin_amdgcn_mfma_f32_16x16x32_f16(w1[ks][1], af, acc1[m][1], 0, 0, 0);
        }
    }

    // ---- prefetch GEMM2 weights (w1 dead, regs recycle); latency hides
    // under the barrier + h-store below.
    f16x8 w2[12][2];
#pragma unroll
    for (int ks = 0; ks < 12; ++ks) {
        const int j  = ks >> 2;
        const int c0 = (ks & 3) << 5;
        const _Float16* wb = Wt2 + (size_t)j * (CH * CH) + c0 + kg * 8;
        w2[ks][0] = *(const f16x8*)(wb + (nc + l15) * CH);
        w2[ks][1] = *(const f16x8*)(wb + (nc + 16 + l15) * CH);
    }

    // all waves done READING the x window before h overwrites it
    __syncthreads();

    // ---- store h rows 0..143 into the SAME buffer (relu + bias)
    // lane holds f-consecutive quad at row u = t0 + m*16 + l15 -> ds_write_b64
#pragma unroll
    for (int m = 0; m < 9; ++m) {
        const int r  = m * 16 + l15;
        const int u  = t0 + r;
        const float nv = (float)(1 + (u < TLEN - DIL) + (u < TLEN - 2 * DIL));
        const bool ok = (u < TLEN);
#pragma unroll
        for (int nn = 0; nn < 2; ++nn) {
            const f32x4 bv = nn ? bv1_1 : bv1_0;
            f16x4 hv;
#pragma unroll
            for (int i = 0; i < 4; ++i) {
                float v = acc1[m][nn][i] + nv * bv[i];
                v = fmaxf(v, 0.0f);
                hv[i] = ok ? (_Float16)v : (_Float16)0.0f;
            }
            *(f16x4*)&buf[r][nc + nn * 16 + kg * 4] = hv;
        }
    }
    __syncthreads();

    // ---- GEMM2: out rows 0..127, cols [nc,nc+32) — 192 MFMA / 96 ds_read
    f32x4 acc2[8][2];
#pragma unroll
    for (int m = 0; m < 8; ++m) {
        acc2[m][0] = (f32x4){0.f, 0.f, 0.f, 0.f};
        acc2[m][1] = (f32x4){0.f, 0.f, 0.f, 0.f};
    }
#pragma unroll
    for (int ks = 0; ks < 12; ++ks) {
        const int j     = ks >> 2;
        const int c0    = (ks & 3) << 5;
        const int shift = (2 - j) * DIL;
#pragma unroll
        for (int m = 0; m < 8; ++m) {
            f16x8 af = *(const f16x8*)&buf[m * 16 + shift + l15][c0 + kg * 8];
            acc2[m][0] = __builtin_amdgcn_mfma_f32_16x16x32_f16(w2[ks][0], af, acc2[m][0], 0, 0, 0);
            acc2[m][1] = __builtin_amdgcn_mfma_f32_16x16x32_f16(w2[ks][1], af, acc2[m][1], 0, 0, 0);
        }
    }

    // ---- epilogue: bias2 + relu, + residual (f32x4), relu, f32x4 store
#pragma unroll
    for (int m = 0; m < 8; ++m) {
        const int t  = t0 + m * 16 + l15;
        const float nv = (float)(1 + (t < TLEN - DIL) + (t < TLEN - 2 * DIL));
        const size_t gbase = ((size_t)b * TLEN + t) * CH + nc + kg * 4;
#pragma unroll
        for (int nn = 0; nn < 2; ++nn) {
            const f32x4 bv = nn ? bv2_1 : bv2_0;
            const size_t gi = gbase + nn * 16;
            const f32x4 rx = *(const f32x4*)&x[gi];
            f32x4 o;
#pragma unroll
            for (int i = 0; i < 4; ++i) {
                float v = acc2[m][nn][i] + nv * bv[i];
                v = fmaxf(v, 0.0f);
                v = fmaxf(v + rx[i], 0.0f);
                o[i] = v;
            }
            *(f32x4*)&out[gi] = o;
        }
    }
}

// ---------------------------------------------------------------------------
extern "C" void kernel_launch(void* const* d_in, const int* in_sizes, int n_in,
                              void* d_out, int out_size, void* d_ws, size_t ws_size,
                              hipStream_t stream) {
    const float* x  = (const float*)d_in[0];
    const float* W1 = (const float*)d_in[1];
    const float* b1 = (const float*)d_in[2];
    const float* W2 = (const float*)d_in[3];
    const float* b2 = (const float*)d_in[4];
    float* out = (float*)d_out;

    _Float16* Wt1 = (_Float16*)d_ws;
    _Float16* Wt2 = Wt1 + KW * CH * CH;

    prep_weights_kernel<<<(2 * KW * CH * CH + 255) / 256, 256, 0, stream>>>(W1, W2, Wt1, Wt2);

    const int grid = BATCH * (TLEN / BM);   // 1024 blocks (= 8 XCDs x 128)
    fused_deconv_kernel<<<grid, 256, 0, stream>>>(x, Wt1, b1, Wt2, b2, out);
}

// Round 14
// 66.616 us; speedup vs baseline: 1.1403x; 1.1403x over previous
//
#include <hip/hip_runtime.h>
#include <hip/hip_fp16.h>

#define BATCH 32
#define TLEN  4096
#define CH    128      // C == F == 128
#define KW    3
#define DIL   8

#define BM    128                // output rows per block
#define HR    (BM + 2 * DIL)     // 144  h rows needed
#define WROWS (BM + 4 * DIL)     // 160  x rows needed
#define LDSC  132                // 264B stride = 66 dwords ≡ 2 (mod 32): ~2-way
                                 // bank alias (free). 136 (≡4 mod 32) gave 8-way
                                 // conflicts (r6-r11). Keep stride ≢ 0/4 mod 32.

typedef _Float16 f16x8 __attribute__((ext_vector_type(8)));
typedef float    f32x4 __attribute__((ext_vector_type(4)));

// ---------------------------------------------------------------------------
// Prep: Wt[j][f][c] = (f16) W[c][j][f]   for both layers' kernels.
// W is (C, K, F) row-major: W[c*KW*CH + j*CH + f].
// ---------------------------------------------------------------------------
__global__ void prep_weights_kernel(const float* __restrict__ W1,
                                    const float* __restrict__ W2,
                                    _Float16* __restrict__ Wt1,
                                    _Float16* __restrict__ Wt2) {
    const int total = KW * CH * CH;
    int idx = blockIdx.x * 256 + threadIdx.x;
    if (idx >= 2 * total) return;
    const float* W  = (idx < total) ? W1 : W2;
    _Float16*    Wt = (idx < total) ? Wt1 : Wt2;
    int r = idx % total;
    int j = r / (CH * CH);
    int f = (r / CH) % CH;
    int c = r % CH;
    Wt[j * CH * CH + f * CH + c] = (_Float16)W[c * (KW * CH) + j * CH + f];
}

// ---------------------------------------------------------------------------
// Fused TemporalDeConvBlock — r12 base (best measured: 67.2us) with two cuts:
//   * separate xs/hs buffers (80.3 KB, still 2 blocks/CU at VGPR 196): the
//     alias-protection barrier is GONE -> 2 barriers total;
//   * residual from the live xs window (f16) -> no 64MB global re-read, no
//     epilogue load latency chain.
// 256 thr = 4 waves; wave w owns cols [32w,32w+32) as two 16-col subtiles
// (each A ds_read feeds 2 MFMA). BM=128 x-window staged once; unswapped
// MFMA (r13's swapped-operand D^T regressed: write-bank collisions + broken
// schedule). XCD-aware bijective block swizzle (grid 1024 = 8*128).
// LESSONS: caps below live-set spill (r3/r5); 512-thr blocks pinned to 64
// VGPR (r4/r6/r7); occupancy not the limiter (r8 vs r11); LDSC mod-32 rule;
// per-thread instr count not the limiter (r13).
// ---------------------------------------------------------------------------
__global__ __launch_bounds__(256)
void fused_deconv_kernel(const float* __restrict__ x,
                         const _Float16* __restrict__ Wt1,
                         const float* __restrict__ bias1,
                         const _Float16* __restrict__ Wt2,
                         const float* __restrict__ bias2,
                         float* __restrict__ out)
{
    __shared__ __align__(16) _Float16 xs[WROWS][LDSC];   // 160*264 = 42240 B
    __shared__ __align__(16) _Float16 hs[HR][LDSC];      // 144*264 = 38016 B

    const int tid  = threadIdx.x;
    const int lane = tid & 63;
    const int wid  = tid >> 6;         // 0..3
    const int l15  = lane & 15;
    const int kg   = lane >> 4;        // 0..3
    const int nc   = wid << 5;         // wave column base: 0,32,64,96

    // XCD-aware bijective swizzle: grid = 1024 = 8 XCDs x 128 chunks.
    const int bt0 = blockIdx.x;
    const int bt  = (bt0 & 7) * 128 + (bt0 >> 3);

    const int b  = bt >> 5;            // TLEN/BM = 32 tiles per batch
    const int t0 = (bt & 31) << 7;

    // ---- prefetch GEMM1 weight fragments (24 x 16B = 96 VGPRs); L2 latency
    // overlaps the x staging below.
    f16x8 w1[12][2];
#pragma unroll
    for (int ks = 0; ks < 12; ++ks) {
        const int j  = ks >> 2;
        const int c0 = (ks & 3) << 5;
        const _Float16* wb = Wt1 + (size_t)j * (CH * CH) + c0 + kg * 8;
        w1[ks][0] = *(const f16x8*)(wb + (nc + l15) * CH);
        w1[ks][1] = *(const f16x8*)(wb + (nc + 16 + l15) * CH);
    }

    // ---- stage x window (f32 -> f16), rows t0..t0+159, zero past TLEN.
#pragma unroll
    for (int p = 0; p < 10; ++p) {
        const int i   = tid + 256 * p;
        const int row = i >> 4;
        const int c8  = (i & 15) << 3;
        const int t   = t0 + row;
        f16x8 o;
        if (t < TLEN) {
            const float* xp = x + ((size_t)b * TLEN + t) * CH + c8;
            f32x4 v0 = *(const f32x4*)(xp + 0);
            f32x4 v1 = *(const f32x4*)(xp + 4);
            o[0] = (_Float16)v0[0]; o[1] = (_Float16)v0[1];
            o[2] = (_Float16)v0[2]; o[3] = (_Float16)v0[3];
            o[4] = (_Float16)v1[0]; o[5] = (_Float16)v1[1];
            o[6] = (_Float16)v1[2]; o[7] = (_Float16)v1[3];
        } else {
            o = (f16x8){};
        }
        *(f16x8*)&xs[row][c8] = o;
    }

    const float bv1_0 = 128.0f * bias1[nc + l15];
    const float bv1_1 = 128.0f * bias1[nc + 16 + l15];
    const float bv2_0 = 128.0f * bias2[nc + l15];
    const float bv2_1 = 128.0f * bias2[nc + 16 + l15];

    __syncthreads();   // barrier 1: xs published

    // ---- GEMM1: h rows 0..143, cols [nc,nc+32) — 216 MFMA / 108 ds_read
    f32x4 acc1[9][2];
#pragma unroll
    for (int m = 0; m < 9; ++m) {
        acc1[m][0] = (f32x4){0.f, 0.f, 0.f, 0.f};
        acc1[m][1] = (f32x4){0.f, 0.f, 0.f, 0.f};
    }
#pragma unroll
    for (int ks = 0; ks < 12; ++ks) {
        const int j     = ks >> 2;
        const int c0    = (ks & 3) << 5;
        const int shift = (2 - j) * DIL;
#pragma unroll
        for (int m = 0; m < 9; ++m) {
            f16x8 af = *(const f16x8*)&xs[m * 16 + shift + l15][c0 + kg * 8];
            acc1[m][0] = __builtin_amdgcn_mfma_f32_16x16x32_f16(af, w1[ks][0], acc1[m][0], 0, 0, 0);
            acc1[m][1] = __builtin_amdgcn_mfma_f32_16x16x32_f16(af, w1[ks][1], acc1[m][1], 0, 0, 0);
        }
    }

    // ---- prefetch GEMM2 weights (w1 dead, regs recycle); latency hides
    // under the h-store below.
    f16x8 w2[12][2];
#pragma unroll
    for (int ks = 0; ks < 12; ++ks) {
        const int j  = ks >> 2;
        const int c0 = (ks & 3) << 5;
        const _Float16* wb = Wt2 + (size_t)j * (CH * CH) + c0 + kg * 8;
        w2[ks][0] = *(const f16x8*)(wb + (nc + l15) * CH);
        w2[ks][1] = *(const f16x8*)(wb + (nc + 16 + l15) * CH);
    }

    // ---- store h rows 0..143 into hs (relu + bias) — no alias barrier needed
#pragma unroll
    for (int m = 0; m < 9; ++m) {
#pragma unroll
        for (int nn = 0; nn < 2; ++nn) {
            const float bv = nn ? bv1_1 : bv1_0;
            const int f = nc + nn * 16 + l15;
#pragma unroll
            for (int i = 0; i < 4; ++i) {
                const int r = m * 16 + kg * 4 + i;
                const int u = t0 + r;
                const int nv = 1 + (u < TLEN - DIL) + (u < TLEN - 2 * DIL);
                float v = acc1[m][nn][i] + (float)nv * bv;
                v = fmaxf(v, 0.0f);
                hs[r][f] = (u < TLEN) ? (_Float16)v : (_Float16)0.0f;
            }
        }
    }
    __syncthreads();   // barrier 2: hs published

    // ---- GEMM2: out rows 0..127, cols [nc,nc+32) — 192 MFMA / 96 ds_read
    f32x4 acc2[8][2];
#pragma unroll
    for (int m = 0; m < 8; ++m) {
        acc2[m][0] = (f32x4){0.f, 0.f, 0.f, 0.f};
        acc2[m][1] = (f32x4){0.f, 0.f, 0.f, 0.f};
    }
#pragma unroll
    for (int ks = 0; ks < 12; ++ks) {
        const int j     = ks >> 2;
        const int c0    = (ks & 3) << 5;
        const int shift = (2 - j) * DIL;
#pragma unroll
        for (int m = 0; m < 8; ++m) {
            f16x8 af = *(const f16x8*)&hs[m * 16 + shift + l15][c0 + kg * 8];
            acc2[m][0] = __builtin_amdgcn_mfma_f32_16x16x32_f16(af, w2[ks][0], acc2[m][0], 0, 0, 0);
            acc2[m][1] = __builtin_amdgcn_mfma_f32_16x16x32_f16(af, w2[ks][1], acc2[m][1], 0, 0, 0);
        }
    }

    // ---- epilogue: bias2 + relu, + residual (f16 from live xs window),
    // relu, store f32
#pragma unroll
    for (int m = 0; m < 8; ++m) {
#pragma unroll
        for (int nn = 0; nn < 2; ++nn) {
            const float bv = nn ? bv2_1 : bv2_0;
            const int f = nc + nn * 16 + l15;
#pragma unroll
            for (int i = 0; i < 4; ++i) {
                const int r = m * 16 + kg * 4 + i;
                const int t = t0 + r;
                const int nv = 1 + (t < TLEN - DIL) + (t < TLEN - 2 * DIL);
                float v = acc2[m][nn][i] + (float)nv * bv;
                v = fmaxf(v, 0.0f);
                v = fmaxf(v + (float)xs[r][f], 0.0f);
                out[((size_t)b * TLEN + t) * CH + f] = v;
            }
        }
    }
}

// ---------------------------------------------------------------------------
extern "C" void kernel_launch(void* const* d_in, const int* in_sizes, int n_in,
                              void* d_out, int out_size, void* d_ws, size_t ws_size,
                              hipStream_t stream) {
    const float* x  = (const float*)d_in[0];
    const float* W1 = (const float*)d_in[1];
    const float* b1 = (const float*)d_in[2];
    const float* W2 = (const float*)d_in[3];
    const float* b2 = (const float*)d_in[4];
    float* out = (float*)d_out;

    _Float16* Wt1 = (_Float16*)d_ws;
    _Float16* Wt2 = Wt1 + KW * CH * CH;

    prep_weights_kernel<<<(2 * KW * CH * CH + 255) / 256, 256, 0, stream>>>(W1, W2, Wt1, Wt2);

    const int grid = BATCH * (TLEN / BM);   // 1024 blocks (= 8 XCDs x 128)
    fused_deconv_kernel<<<grid, 256, 0, stream>>>(x, Wt1, b1, Wt2, b2, out);
}

// Round 15
// 66.083 us; speedup vs baseline: 1.1495x; 1.0081x over previous
//
#include <hip/hip_runtime.h>
#include <hip/hip_fp16.h>

#define BATCH 32
#define TLEN  4096
#define CH    128      // C == F == 128
#define KW    3
#define DIL   8

#define BM    128                // output rows per block
#define HR    (BM + 2 * DIL)     // 144  h rows needed
#define WROWS (BM + 4 * DIL)     // 160  x rows needed
#define LDSC  132                // 264B stride = 66 dwords ≡ 2 (mod 32): ~2-way
                                 // bank alias (free). 136 (≡4 mod 32) gave 8-way
                                 // conflicts (r6-r11). Keep stride ≢ 0/4 mod 32.

typedef _Float16 f16x8 __attribute__((ext_vector_type(8)));
typedef float    f32x4 __attribute__((ext_vector_type(4)));

// ---------------------------------------------------------------------------
// Prep: Wt[j][f][c] = (f16) W[c][j][f]   for both layers' kernels.
// ---------------------------------------------------------------------------
__global__ void prep_weights_kernel(const float* __restrict__ W1,
                                    const float* __restrict__ W2,
                                    _Float16* __restrict__ Wt1,
                                    _Float16* __restrict__ Wt2) {
    const int total = KW * CH * CH;
    int idx = blockIdx.x * 256 + threadIdx.x;
    if (idx >= 2 * total) return;
    const float* W  = (idx < total) ? W1 : W2;
    _Float16*    Wt = (idx < total) ? Wt1 : Wt2;
    int r = idx % total;
    int j = r / (CH * CH);
    int f = (r / CH) % CH;
    int c = r % CH;
    Wt[j * CH * CH + f * CH + c] = (_Float16)W[c * (KW * CH) + j * CH + f];
}

// ---------------------------------------------------------------------------
// Fused TemporalDeConvBlock — r14 base + RING-PREFETCHED GEMM loops.
// Diagnosis (r14 post-mortem): live set w(96)+acc(72) ~ 170 of 176-200 VGPR
// left no room to keep A-fragments in flight -> each (ks,m) step paid the
// full ~120cy LDS latency: 204 reads x 130cy ~ 27K cy/wave = the entire
// perf gap vs the pipe-busy model. Fix: flatten (ks,m), ring of 8 in-flight
// ds_reads (32 VGPR, compile-time indices): consume afr[i&7] in 2 MFMAs,
// then issue read i+8 into the freed slot (retires ~176cy later > 120cy).
// 256 thr = 4 waves; wave w owns cols [32w,32w+32) as two 16-col subtiles.
// Separate xs/hs buffers (2 barriers), residual from live xs window (f16),
// XCD-aware bijective block swizzle (grid 1024 = 8*128), LDSC=132.
// LESSONS: caps below live-set spill (r3/r5); 512-thr blocks pinned to 64
// VGPR (r4/r6/r7); occupancy/barriers/conflicts/instr-count all proven
// non-binding (r8-r14); watch WRITE_SIZE ~ 65MB as the no-spill invariant.
// ---------------------------------------------------------------------------
__global__ __launch_bounds__(256)
void fused_deconv_kernel(const float* __restrict__ x,
                         const _Float16* __restrict__ Wt1,
                         const float* __restrict__ bias1,
                         const _Float16* __restrict__ Wt2,
                         const float* __restrict__ bias2,
                         float* __restrict__ out)
{
    __shared__ __align__(16) _Float16 xs[WROWS][LDSC];   // 160*264 = 42240 B
    __shared__ __align__(16) _Float16 hs[HR][LDSC];      // 144*264 = 38016 B

    const int tid  = threadIdx.x;
    const int lane = tid & 63;
    const int wid  = tid >> 6;         // 0..3
    const int l15  = lane & 15;
    const int kg   = lane >> 4;        // 0..3
    const int nc   = wid << 5;         // wave column base: 0,32,64,96

    // XCD-aware bijective swizzle: grid = 1024 = 8 XCDs x 128 chunks.
    const int bt0 = blockIdx.x;
    const int bt  = (bt0 & 7) * 128 + (bt0 >> 3);

    const int b  = bt >> 5;            // TLEN/BM = 32 tiles per batch
    const int t0 = (bt & 31) << 7;

    // ---- prefetch GEMM1 weight fragments (24 x 16B = 96 VGPRs); L2 latency
    // overlaps the x staging below.
    f16x8 w1[12][2];
#pragma unroll
    for (int ks = 0; ks < 12; ++ks) {
        const int j  = ks >> 2;
        const int c0 = (ks & 3) << 5;
        const _Float16* wb = Wt1 + (size_t)j * (CH * CH) + c0 + kg * 8;
        w1[ks][0] = *(const f16x8*)(wb + (nc + l15) * CH);
        w1[ks][1] = *(const f16x8*)(wb + (nc + 16 + l15) * CH);
    }

    // ---- stage x window (f32 -> f16), rows t0..t0+159, zero past TLEN.
#pragma unroll
    for (int p = 0; p < 10; ++p) {
        const int i   = tid + 256 * p;
        const int row = i >> 4;
        const int c8  = (i & 15) << 3;
        const int t   = t0 + row;
        f16x8 o;
        if (t < TLEN) {
            const float* xp = x + ((size_t)b * TLEN + t) * CH + c8;
            f32x4 v0 = *(const f32x4*)(xp + 0);
            f32x4 v1 = *(const f32x4*)(xp + 4);
            o[0] = (_Float16)v0[0]; o[1] = (_Float16)v0[1];
            o[2] = (_Float16)v0[2]; o[3] = (_Float16)v0[3];
            o[4] = (_Float16)v1[0]; o[5] = (_Float16)v1[1];
            o[6] = (_Float16)v1[2]; o[7] = (_Float16)v1[3];
        } else {
            o = (f16x8){};
        }
        *(f16x8*)&xs[row][c8] = o;
    }

    const float bv1_0 = 128.0f * bias1[nc + l15];
    const float bv1_1 = 128.0f * bias1[nc + 16 + l15];
    const float bv2_0 = 128.0f * bias2[nc + l15];
    const float bv2_1 = 128.0f * bias2[nc + 16 + l15];

    __syncthreads();   // barrier 1: xs published

    // ---- GEMM1: h rows 0..143, cols [nc,nc+32) — 216 MFMA / 108 ds_read,
    // flattened (ks,m) with an 8-deep read ring.
    f32x4 acc1[9][2];
#pragma unroll
    for (int m = 0; m < 9; ++m) {
        acc1[m][0] = (f32x4){0.f, 0.f, 0.f, 0.f};
        acc1[m][1] = (f32x4){0.f, 0.f, 0.f, 0.f};
    }
    {
        // LD1(i): ks = i/9, m = i%9 (compile-time under full unroll)
#define LD1(i) (*(const f16x8*)&xs[((i) % 9) * 16 + (2 - ((i) / 9) / 4) * DIL + l15] \
                                  [((((i) / 9) & 3) << 5) + kg * 8])
        f16x8 afr[8];
#pragma unroll
        for (int i = 0; i < 8; ++i) afr[i] = LD1(i);
#pragma unroll
        for (int i = 0; i < 108; ++i) {
            const int ks = i / 9;
            const int m  = i % 9;
            acc1[m][0] = __builtin_amdgcn_mfma_f32_16x16x32_f16(afr[i & 7], w1[ks][0], acc1[m][0], 0, 0, 0);
            acc1[m][1] = __builtin_amdgcn_mfma_f32_16x16x32_f16(afr[i & 7], w1[ks][1], acc1[m][1], 0, 0, 0);
            if (i + 8 < 108) afr[i & 7] = LD1(i + 8);
        }
#undef LD1
    }

    // ---- prefetch GEMM2 weights (w1 dead, regs recycle); latency hides
    // under the h-store below.
    f16x8 w2[12][2];
#pragma unroll
    for (int ks = 0; ks < 12; ++ks) {
        const int j  = ks >> 2;
        const int c0 = (ks & 3) << 5;
        const _Float16* wb = Wt2 + (size_t)j * (CH * CH) + c0 + kg * 8;
        w2[ks][0] = *(const f16x8*)(wb + (nc + l15) * CH);
        w2[ks][1] = *(const f16x8*)(wb + (nc + 16 + l15) * CH);
    }

    // ---- store h rows 0..143 into hs (relu + bias)
#pragma unroll
    for (int m = 0; m < 9; ++m) {
#pragma unroll
        for (int nn = 0; nn < 2; ++nn) {
            const float bv = nn ? bv1_1 : bv1_0;
            const int f = nc + nn * 16 + l15;
#pragma unroll
            for (int i = 0; i < 4; ++i) {
                const int r = m * 16 + kg * 4 + i;
                const int u = t0 + r;
                const int nv = 1 + (u < TLEN - DIL) + (u < TLEN - 2 * DIL);
                float v = acc1[m][nn][i] + (float)nv * bv;
                v = fmaxf(v, 0.0f);
                hs[r][f] = (u < TLEN) ? (_Float16)v : (_Float16)0.0f;
            }
        }
    }
    __syncthreads();   // barrier 2: hs published

    // ---- GEMM2: out rows 0..127, cols [nc,nc+32) — 192 MFMA / 96 ds_read,
    // same 8-deep read ring.
    f32x4 acc2[8][2];
#pragma unroll
    for (int m = 0; m < 8; ++m) {
        acc2[m][0] = (f32x4){0.f, 0.f, 0.f, 0.f};
        acc2[m][1] = (f32x4){0.f, 0.f, 0.f, 0.f};
    }
    {
#define LD2(i) (*(const f16x8*)&hs[((i) % 8) * 16 + (2 - ((i) / 8) / 4) * DIL + l15] \
                                  [((((i) / 8) & 3) << 5) + kg * 8])
        f16x8 afr[8];
#pragma unroll
        for (int i = 0; i < 8; ++i) afr[i] = LD2(i);
#pragma unroll
        for (int i = 0; i < 96; ++i) {
            const int ks = i / 8;
            const int m  = i % 8;
            acc2[m][0] = __builtin_amdgcn_mfma_f32_16x16x32_f16(afr[i & 7], w2[ks][0], acc2[m][0], 0, 0, 0);
            acc2[m][1] = __builtin_amdgcn_mfma_f32_16x16x32_f16(afr[i & 7], w2[ks][1], acc2[m][1], 0, 0, 0);
            if (i + 8 < 96) afr[i & 7] = LD2(i + 8);
        }
#undef LD2
    }

    // ---- epilogue: bias2 + relu, + residual (f16 from live xs window),
    // relu, store f32
#pragma unroll
    for (int m = 0; m < 8; ++m) {
#pragma unroll
        for (int nn = 0; nn < 2; ++nn) {
            const float bv = nn ? bv2_1 : bv2_0;
            const int f = nc + nn * 16 + l15;
#pragma unroll
            for (int i = 0; i < 4; ++i) {
                const int r = m * 16 + kg * 4 + i;
                const int t = t0 + r;
                const int nv = 1 + (t < TLEN - DIL) + (t < TLEN - 2 * DIL);
                float v = acc2[m][nn][i] + (float)nv * bv;
                v = fmaxf(v, 0.0f);
                v = fmaxf(v + (float)xs[r][f], 0.0f);
                out[((size_t)b * TLEN + t) * CH + f] = v;
            }
        }
    }
}

// ---------------------------------------------------------------------------
extern "C" void kernel_launch(void* const* d_in, const int* in_sizes, int n_in,
                              void* d_out, int out_size, void* d_ws, size_t ws_size,
                              hipStream_t stream) {
    const float* x  = (const float*)d_in[0];
    const float* W1 = (const float*)d_in[1];
    const float* b1 = (const float*)d_in[2];
    const float* W2 = (const float*)d_in[3];
    const float* b2 = (const float*)d_in[4];
    float* out = (float*)d_out;

    _Float16* Wt1 = (_Float16*)d_ws;
    _Float16* Wt2 = Wt1 + KW * CH * CH;

    prep_weights_kernel<<<(2 * KW * CH * CH + 255) / 256, 256, 0, stream>>>(W1, W2, Wt1, Wt2);

    const int grid = BATCH * (TLEN / BM);   // 1024 blocks (= 8 XCDs x 128)
    fused_deconv_kernel<<<grid, 256, 0, stream>>>(x, Wt1, b1, Wt2, b2, out);
}